// Round 9
// baseline (300.585 us; speedup 1.0000x reference)
//
#include <hip/hip_runtime.h>
#include <hip/hip_fp16.h>
#include <math.h>

#define NPTS 4096
#define CDIM 128
#define FH 120
#define FW 160
#define PIX (FH * FW)   // 19200
#define SEGS 8

typedef __attribute__((ext_vector_type(8))) short short8_t;
typedef __attribute__((ext_vector_type(4))) float float4_t;
typedef __attribute__((ext_vector_type(2))) unsigned short ushort2_t;

// workspace layout (float offsets)
#define OFF_FRAG  0                    // [b][tile 256][chunk 8][lane 64][8 bf16] = 4MB
#define OFF_WDB   1048576              // wd row layout (d22 recompute)
#define OFF_JA    1572864              // float4/pt: (ky,kx,wky,wkx)
#define OFF_JB    1605632              // float2/pt: (|d1|^2, |wd|^2)
#define OFF_POS   1622016
#define OFF_VIS   1630208
#define OFF_ACC   1638400              // [0]=loss [1]=vis [2]=final counter
#define OFF_CNT   1638416              // 512 ints: per-anchor-tile segment counters
#define OFF_PARTS 1638928              // 8 segs * 22 lists * 8192 anchors
#define OFF_D2T   3080720              // fp16 transposed desc2
#define OFF_END   4309520

typedef const __attribute__((address_space(1))) unsigned int* gas_ptr_t;
typedef __attribute__((address_space(3))) unsigned int* las_ptr_t;

__device__ __forceinline__ void dma16(const void* g, void* l) {
  __builtin_amdgcn_global_load_lds((gas_ptr_t)g, (las_ptr_t)l, 16, 0, 0);
}

__device__ __forceinline__ unsigned short f2bf(float f) {
  unsigned int u = __float_as_uint(f);
  u = (u + 0x7fffu + ((u >> 16) & 1u)) >> 16;  // RNE, no NaN in this data
  return (unsigned short)u;
}

__device__ __forceinline__ float wavesum(float v) {
#pragma unroll
  for (int off = 1; off < 64; off <<= 1) v += __shfl_xor(v, off, 64);
  return v;
}

// ---- desc2 [b][c][pix] f32 -> [b][pix][c] f16 ----
__global__ __launch_bounds__(256) void transpose_desc2(
    const float* __restrict__ d2, unsigned short* __restrict__ out) {
  __shared__ unsigned short tile[64][130];
  const int bp = blockIdx.x;            // 0..599
  const int b = bp / 300;
  const int p0 = (bp - b * 300) * 64;
  const int tid = threadIdx.x;
  const int grp = tid >> 6, lp = tid & 63;
#pragma unroll 4
  for (int r = 0; r < 32; ++r) {
    int c = (r << 2) | grp;
    float v = d2[((size_t)b * CDIM + c) * PIX + p0 + lp];
    tile[lp][c] = __half_as_ushort(__float2half(v));
  }
  __syncthreads();
  unsigned int* ob = (unsigned int*)(out + ((size_t)b * PIX + p0) * CDIM);
#pragma unroll
  for (int i = 0; i < 16; ++i) {
    int u = (i << 8) | tid;
    int p = u >> 6, cc = (u & 63) << 1;
    unsigned int lo = tile[p][cc], hi = tile[p][cc + 1];
    ob[u] = lo | (hi << 16);
  }
}

// shared tail of both prep variants (frag-stream + scalar writes + counter init)
#define PREP_TAIL() do {                                                        \
  {                                                                             \
    const int T = (p & (NPTS - 1)) >> 4, cRow = p & 15;                         \
    const int kcL = lane >> 4, quadL = (lane >> 2) & 3, jjL = (lane & 3) * 2;   \
    const size_t off = (size_t)(quadL * 16 + cRow) * 8 + jjL;                   \
    const size_t tb = (((size_t)b * 256 + T) * 2) * 4;                          \
    ushort2_t st; st.x = f2bf(d0); st.y = f2bf(d1v);                            \
    ushort2_t sw; sw.x = f2bf(e0); sw.y = f2bf(e1);                             \
    *(ushort2_t*)(frag + (tb + kcL) * 512 + off) = st;                          \
    *(ushort2_t*)(frag + (tb + 4 + kcL) * 512 + off) = sw;                      \
    ushort2_t swr; swr.x = f2bf(e0); swr.y = f2bf(e1);                          \
    *(ushort2_t*)(wdb + (size_t)p * CDIM + c2) = swr;                           \
  }                                                                             \
  float dd0 = d0 - e0, dd1 = d1v - e1;                                          \
  float ssp = wavesum(dd0 * dd0 + dd1 * dd1);                                   \
  if (lane == 0) {                                                              \
    pos[p] = sqrtf(ssp + 1e-12f);                                               \
    float ky = kp1[p * 2 + 0], kx = kp1[p * 2 + 1];                             \
    jA[p] = make_float4(ky, kx, y, x);                                          \
    jB[p] = make_float2(n1, n2);                                                \
    const float* h = homo + b * 9;                                              \
    float t0 = h[0] * kx + h[1] * ky + h[2];                                    \
    float t1 = h[3] * kx + h[4] * ky + h[5];                                    \
    float t2 = h[6] * kx + h[7] * ky + h[8];                                    \
    float qx = t0 / (t2 + 1e-8f), qy = t1 / (t2 + 1e-8f);                       \
    vis[p] = (qx >= 0.0f && qx < 1280.0f && qy >= 0.0f && qy < 960.0f)          \
                 ? 1.0f : 0.0f;                                                 \
  }                                                                             \
} while (0)

#define PREP_INIT() do {                                                        \
  if (blockIdx.x < 2) cnt[blockIdx.x * 256 + tid] = 0;                          \
  if (blockIdx.x == 2 && tid < 8) acc[tid] = 0.0f;                              \
} while (0)

__global__ __launch_bounds__(256) void prep_t(
    const float* __restrict__ kp1, const float* __restrict__ wkp1,
    const float* __restrict__ desc, const unsigned short* __restrict__ d2t,
    const float* __restrict__ homo,
    unsigned short* __restrict__ frag, unsigned short* __restrict__ wdb,
    float4* __restrict__ jA, float2* __restrict__ jB,
    float* __restrict__ pos, float* __restrict__ vis,
    float* __restrict__ acc, int* __restrict__ cnt) {
  const int tid = threadIdx.x;
  PREP_INIT();
  const int p = blockIdx.x * 4 + (tid >> 6);
  const int lane = tid & 63;
  const int b = p >> 12;
  const int c2 = lane * 2;

  float2 v = *(const float2*)(desc + (size_t)p * CDIM + c2);
  float ss = wavesum(v.x * v.x + v.y * v.y);
  float inv = 1.0f / (sqrtf(ss) + 1e-8f);
  float d0 = v.x * inv, d1v = v.y * inv;
  float n1 = ss * inv * inv;

  float y = wkp1[p * 2 + 0], x = wkp1[p * 2 + 1];
  float gy = fminf(fmaxf(y * 0.125f - 0.5f, 0.0f), (float)(FH - 1));
  float gx = fminf(fmaxf(x * 0.125f - 0.5f, 0.0f), (float)(FW - 1));
  int y0 = (int)floorf(gy); y0 = min(max(y0, 0), FH - 2);
  int x0 = (int)floorf(gx); x0 = min(max(x0, 0), FW - 2);
  float wy = gy - (float)y0, wx = gx - (float)x0;
  float w00 = (1 - wy) * (1 - wx), w01 = (1 - wy) * wx;
  float w10 = wy * (1 - wx), w11 = wy * wx;
  const unsigned int* t00 = (const unsigned int*)
      (d2t + ((size_t)b * PIX + y0 * FW + x0) * CDIM) + lane;
  unsigned int u00 = t00[0], u01 = t00[64];
  unsigned int u10 = t00[FW * 64], u11 = t00[FW * 64 + 64];
  float2 f00 = __half22float2(*(const __half2*)&u00);
  float2 f01 = __half22float2(*(const __half2*)&u01);
  float2 f10 = __half22float2(*(const __half2*)&u10);
  float2 f11 = __half22float2(*(const __half2*)&u11);
  float wv0 = f00.x * w00 + f01.x * w01 + f10.x * w10 + f11.x * w11;
  float wv1 = f00.y * w00 + f01.y * w01 + f10.y * w10 + f11.y * w11;
  float ss2 = wavesum(wv0 * wv0 + wv1 * wv1);
  float inv2 = 1.0f / (sqrtf(ss2) + 1e-8f);
  float e0 = wv0 * inv2, e1 = wv1 * inv2;
  float n2 = ss2 * inv2 * inv2;

  PREP_TAIL();
}

__global__ __launch_bounds__(256) void prep_g(
    const float* __restrict__ kp1, const float* __restrict__ wkp1,
    const float* __restrict__ desc, const float* __restrict__ desc2,
    const float* __restrict__ homo,
    unsigned short* __restrict__ frag, unsigned short* __restrict__ wdb,
    float4* __restrict__ jA, float2* __restrict__ jB,
    float* __restrict__ pos, float* __restrict__ vis,
    float* __restrict__ acc, int* __restrict__ cnt) {
  const int tid = threadIdx.x;
  PREP_INIT();
  const int p = blockIdx.x * 4 + (tid >> 6);
  const int lane = tid & 63;
  const int b = p >> 12;
  const int c2 = lane * 2;

  float2 v = *(const float2*)(desc + (size_t)p * CDIM + c2);
  float ss = wavesum(v.x * v.x + v.y * v.y);
  float inv = 1.0f / (sqrtf(ss) + 1e-8f);
  float d0 = v.x * inv, d1v = v.y * inv;
  float n1 = ss * inv * inv;

  float y = wkp1[p * 2 + 0], x = wkp1[p * 2 + 1];
  float gy = fminf(fmaxf(y * 0.125f - 0.5f, 0.0f), (float)(FH - 1));
  float gx = fminf(fmaxf(x * 0.125f - 0.5f, 0.0f), (float)(FW - 1));
  int y0 = (int)floorf(gy); y0 = min(max(y0, 0), FH - 2);
  int x0 = (int)floorf(gx); x0 = min(max(x0, 0), FW - 2);
  float wy = gy - (float)y0, wx = gx - (float)x0;
  float w00 = (1 - wy) * (1 - wx), w01 = (1 - wy) * wx;
  float w10 = wy * (1 - wx), w11 = wy * wx;
  const float* q0 = desc2 + ((size_t)b * CDIM + c2) * PIX + y0 * FW + x0;
  const float* q1 = q0 + PIX;
  float wv0 = q0[0] * w00 + q0[1] * w01 + q0[FW] * w10 + q0[FW + 1] * w11;
  float wv1 = q1[0] * w00 + q1[1] * w01 + q1[FW] * w10 + q1[FW + 1] * w11;
  float ss2 = wavesum(wv0 * wv0 + wv1 * wv1);
  float inv2 = 1.0f / (sqrtf(ss2) + 1e-8f);
  float e0 = wv0 * inv2, e1 = wv1 * inv2;
  float n2 = ss2 * inv2 * inv2;

  PREP_TAIL();
}

// ---- med3 branchless inserts (sorted descending) ----
__device__ __forceinline__ void ins4m(float v, float* L) {
  float p0 = L[0]; L[0] = fmaxf(L[0], v);
  float p1 = L[1]; L[1] = __builtin_amdgcn_fmed3f(p0, L[1], v);
  float p2 = L[2]; L[2] = __builtin_amdgcn_fmed3f(p1, L[2], v);
  L[3] = __builtin_amdgcn_fmed3f(p2, L[3], v);
}
__device__ __forceinline__ void ins6m(float v, float* L) {
  float p0 = L[0]; L[0] = fmaxf(L[0], v);
  float p1 = L[1]; L[1] = __builtin_amdgcn_fmed3f(p0, L[1], v);
  float p2 = L[2]; L[2] = __builtin_amdgcn_fmed3f(p1, L[2], v);
  float p3 = L[3]; L[3] = __builtin_amdgcn_fmed3f(p2, L[3], v);
  float p4 = L[4]; L[4] = __builtin_amdgcn_fmed3f(p3, L[4], v);
  L[5] = __builtin_amdgcn_fmed3f(p4, L[5], v);
}
__device__ __forceinline__ void ins10m(float v, float* L) {
  float p0 = L[0]; L[0] = fmaxf(L[0], v);
  float pk = p0;
#pragma unroll
  for (int k = 1; k < 9; ++k) {
    float cur = L[k];
    L[k] = __builtin_amdgcn_fmed3f(pk, cur, v);
    pk = cur;
  }
  L[9] = __builtin_amdgcn_fmed3f(pk, L[9], v);
}

__device__ __forceinline__ float packkey(float s, int j) {
  return __uint_as_float((__float_as_uint(s) & 0xFFFFF000u) | (unsigned)j);
}

__device__ __forceinline__ float bflo(unsigned int u) { return __uint_as_float(u << 16); }
__device__ __forceinline__ float bfhi(unsigned int u) { return __uint_as_float(u & 0xFFFF0000u); }

// 1024 blocks x 256 threads. bid = (b, seg of 8, grp of 64). The 4 waves share
// the A-stream via LDS double-buffered global_load_lds DMA; wave w owns anchor
// tile grp*4+w (16 anchors). Last segment-wave per anchor-tile merges + filters.
__global__ __launch_bounds__(256, 4) void loss_main(
    const unsigned short* __restrict__ frag,
    const float4* __restrict__ jAg, const float2* __restrict__ jBg,
    const float* __restrict__ posg, const float* __restrict__ visg,
    const unsigned short* __restrict__ wdb,
    float* __restrict__ parts, int* __restrict__ cnt,
    float* __restrict__ accum, float* __restrict__ out) {
  __shared__ char ldsA[2][8192];

  const int tid = threadIdx.x;
  const int bid = blockIdx.x;
  const int b = bid & 1;
  const int seg = (bid >> 1) & 7;
  const int grp = bid >> 4;               // 0..63
  const int wave = tid >> 6, lane = tid & 63;
  const int atile = grp * 4 + wave;       // 0..255
  const int i0 = atile * 16;
  const int quad = lane >> 4;
  const int base = b * NPTS;

  // B fragments (own anchors), resident
  short8_t Bd[4], Bw[4];
  {
    const unsigned short* fb = frag + (((size_t)b * 256 + atile) * 8) * 512 + (size_t)lane * 8;
#pragma unroll
    for (int kc = 0; kc < 4; ++kc) {
      Bd[kc] = *(const short8_t*)(fb + kc * 512);
      Bw[kc] = *(const short8_t*)(fb + (4 + kc) * 512);
    }
  }

  float fD[4], fDt[4], fS[6];
#pragma unroll
  for (int k = 0; k < 4; ++k) { fD[k] = -1e30f; fDt[k] = -1e30f; }
#pragma unroll
  for (int k = 0; k < 6; ++k) fS[k] = -1e30f;

  const int jstart = seg << 9;            // 512 j, 32 tiles
  const unsigned short* ft = frag + (((size_t)b * 256 + (jstart >> 4)) * 8) * 512;

  // preload tile 0 into slot 0 (this wave's 2 chunks)
  {
    const unsigned short* tb0 = ft;
#pragma unroll
    for (int ch = 0; ch < 2; ++ch) {
      int chunk = wave * 2 + ch;
      dma16(tb0 + chunk * 512 + lane * 8, &ldsA[0][chunk * 1024]);
    }
  }
  __syncthreads();

  for (int t = 0; t < 32; ++t) {
    const int cur = t & 1;
    if (t + 1 < 32) {
      const unsigned short* tbn = ft + (size_t)(t + 1) * 4096;
#pragma unroll
      for (int ch = 0; ch < 2; ++ch) {
        int chunk = wave * 2 + ch;
        dma16(tbn + chunk * 512 + lane * 8, &ldsA[cur ^ 1][chunk * 1024]);
      }
    }
    // fragments from LDS
    const char* lb = &ldsA[cur][0];
    short8_t Ad[4], Aw[4];
#pragma unroll
    for (int kc = 0; kc < 4; ++kc) {
      Ad[kc] = *(const short8_t*)(lb + kc * 1024 + lane * 16);
      Aw[kc] = *(const short8_t*)(lb + (4 + kc) * 1024 + lane * 16);
    }
    const int j0 = jstart + (t << 4);
    const float4 nA = *(const float4*)(jBg + base + j0 + (quad << 2));
    const float4 nB = *(const float4*)(jBg + base + j0 + (quad << 2) + 2);

    float4_t aD = {0, 0, 0, 0}, aDt = {0, 0, 0, 0}, a11 = {0, 0, 0, 0};
#pragma unroll
    for (int kc = 0; kc < 4; ++kc) {
      aD  = __builtin_amdgcn_mfma_f32_16x16x32_bf16(Aw[kc], Bd[kc], aD,  0, 0, 0);
      aDt = __builtin_amdgcn_mfma_f32_16x16x32_bf16(Ad[kc], Bw[kc], aDt, 0, 0, 0);
      a11 = __builtin_amdgcn_mfma_f32_16x16x32_bf16(Ad[kc], Bd[kc], a11, 0, 0, 0);
    }
    const float nj1[4] = {nA.x, nA.z, nB.x, nB.z};
    const float nj2[4] = {nA.y, nA.w, nB.y, nB.w};
#pragma unroll
    for (int reg = 0; reg < 4; ++reg) {
      const int jj = j0 + (quad << 2) + reg;
      ins4m(packkey(fmaf(2.0f, aD[reg],  -nj2[reg]), jj), fD);
      ins4m(packkey(fmaf(2.0f, aDt[reg], -nj1[reg]), jj), fDt);
      ins6m(packkey(fmaf(2.0f, a11[reg], -nj1[reg]), jj), fS);
    }
    __syncthreads();
  }

  // expand to 6/6/10 and quad-butterfly (lanes 0..15 end with final seg lists)
  float eD[6], eDt[6], eS[10];
#pragma unroll
  for (int k = 0; k < 4; ++k) { eD[k] = fD[k]; eDt[k] = fDt[k]; }
  eD[4] = eD[5] = eDt[4] = eDt[5] = -1e30f;
#pragma unroll
  for (int k = 0; k < 6; ++k) eS[k] = fS[k];
  eS[6] = eS[7] = eS[8] = eS[9] = -1e30f;
  {
    float tmp[10];
#pragma unroll
    for (int off = 16; off <= 32; off <<= 1) {
#pragma unroll
      for (int k = 0; k < 6; ++k) tmp[k] = eD[k];
#pragma unroll
      for (int k = 0; k < 6; ++k) ins6m(__shfl_xor(tmp[k], off, 64), eD);
#pragma unroll
      for (int k = 0; k < 6; ++k) tmp[k] = eDt[k];
#pragma unroll
      for (int k = 0; k < 6; ++k) ins6m(__shfl_xor(tmp[k], off, 64), eDt);
#pragma unroll
      for (int k = 0; k < 10; ++k) tmp[k] = eS[k];
#pragma unroll
      for (int k = 0; k < 10; ++k) ins10m(__shfl_xor(tmp[k], off, 64), eS);
    }
  }

  // publish this segment's lists
  if (lane < 16) {
    const int a = base + i0 + lane;
    float* P = parts + (size_t)(seg * 22) * 8192 + a;
#pragma unroll
    for (int k = 0; k < 6; ++k) {
      P[(size_t)k * 8192] = eD[k];
      P[(size_t)(6 + k) * 8192] = eDt[k];
    }
#pragma unroll
    for (int k = 0; k < 10; ++k) P[(size_t)(12 + k) * 8192] = eS[k];
  }
  __threadfence();          // release: parts visible before counter bump
  int old = 0;
  if (lane == 0) old = atomicAdd(&cnt[b * 256 + atile], 1);
  old = __shfl(old, 0, 64);
  if (old != SEGS - 1) return;
  __threadfence();          // acquire: other segments' parts now visible

  // ---- merging wave: combine 8 segments, post-filter, d22, accumulate ----
  char* scr = &ldsA[0][wave * 2048];
  int*   sJ   = (int*)scr;             // 128
  float* sD11 = (float*)(scr + 512);   // 128
  float* sD22 = (float*)(scr + 1024);  // 128
  float* sN2  = (float*)(scr + 1536);  // 16
  float* sFv  = (float*)(scr + 1600);  // 16
  float* sVv  = (float*)(scr + 1664);  // 16

  if (lane < 16) {
    const int a = base + i0 + lane;
#pragma unroll
    for (int s = 0; s < SEGS; ++s) {
      if (s == seg) continue;
      const float* Q = parts + (size_t)(s * 22) * 8192 + a;
#pragma unroll
      for (int k = 0; k < 6; ++k) {
        ins6m(Q[(size_t)k * 8192], eD);
        ins6m(Q[(size_t)(6 + k) * 8192], eDt);
      }
#pragma unroll
      for (int k = 0; k < 10; ++k) ins10m(Q[(size_t)(12 + k) * 8192], eS);
    }
    const float4 own = jAg[a];
    const float2 nb = jBg[a];
    const float pv = posg[a], vv = visg[a];
    float t1s = 0.0f, t2s = 0.0f;
    int got = 0;
#pragma unroll
    for (int k = 0; k < 6; ++k) {
      int j = (int)(__float_as_uint(eD[k]) & 0xFFFu);
      float4 jc = jAg[base + j];
      float dz = own.z - jc.z, dw = own.w - jc.w;
      if (got < 4 && dz * dz + dw * dw > 256.0f) {
        float d2 = nb.x - eD[k];
        t1s += fmaxf(1.0f + pv - sqrtf(fmaxf(d2, 1e-12f)), 0.0f);
        got++;
      }
    }
    got = 0;
#pragma unroll
    for (int k = 0; k < 6; ++k) {
      int j = (int)(__float_as_uint(eDt[k]) & 0xFFFu);
      float4 jc = jAg[base + j];
      float dz = own.z - jc.z, dw = own.w - jc.w;
      if (got < 4 && dz * dz + dw * dw > 256.0f) {
        float d2 = nb.y - eDt[k];
        t2s += fmaxf(1.0f + pv - sqrtf(fmaxf(d2, 1e-12f)), 0.0f);
        got++;
      }
    }
    int m = 0;
#pragma unroll
    for (int k = 0; k < 10; ++k) {
      int j = (int)(__float_as_uint(eS[k]) & 0xFFFu);
      float4 jc = jAg[base + j];
      float ay = own.x - jc.x, ax = own.y - jc.y;
      float wz = own.z - jc.z, ww = own.w - jc.w;
      if (m < 8 && ay * ay + ax * ax > 256.0f && wz * wz + ww * ww > 256.0f) {
        sJ[lane * 8 + m] = base + j;
        sD11[lane * 8 + m] = sqrtf(fmaxf(nb.x - eS[k], 1e-12f));
        m++;
      }
    }
    for (int k = m; k < 8; ++k) sJ[lane * 8 + k] = -1;
    sFv[lane] = vv * 0.125f * (t1s + t2s);
    sVv[lane] = vv;
    sN2[lane] = nb.y;
  }
  asm volatile("" ::: "memory");  // wave-internal LDS ordering (DS pipe in-order)

  // d22 for survivors: 128 slots, 2 per lane
#pragma unroll
  for (int rep = 0; rep < 2; ++rep) {
    const int slot = lane + rep * 64;
    const int al = slot >> 3;
    const int j = sJ[slot];
    float d22 = 0.0f;
    if (j >= 0) {
      const uint4* pi = (const uint4*)(wdb + (size_t)(base + i0 + al) * CDIM);
      const uint4* pj = (const uint4*)(wdb + (size_t)j * CDIM);
      float dot = 0.0f;
#pragma unroll
      for (int qq = 0; qq < 16; ++qq) {
        uint4 ui = pi[qq], uj = pj[qq];
        dot = fmaf(bflo(ui.x), bflo(uj.x), dot); dot = fmaf(bfhi(ui.x), bfhi(uj.x), dot);
        dot = fmaf(bflo(ui.y), bflo(uj.y), dot); dot = fmaf(bfhi(ui.y), bfhi(uj.y), dot);
        dot = fmaf(bflo(ui.z), bflo(uj.z), dot); dot = fmaf(bfhi(ui.z), bfhi(uj.z), dot);
        dot = fmaf(bflo(ui.w), bflo(uj.w), dot); dot = fmaf(bfhi(ui.w), bfhi(uj.w), dot);
      }
      d22 = sqrtf(fmaxf(sN2[al] + jBg[j].y - 2.0f * dot, 1e-12f));
    }
    sD22[slot] = d22;
  }
  asm volatile("" ::: "memory");

  float contrib = 0.0f, vsum = 0.0f;
  if (lane < 16) {
    float s = 0.0f;
#pragma unroll
    for (int k = 0; k < 8; ++k) {
      if (sJ[lane * 8 + k] >= 0) {
        float d = sD11[lane * 8 + k] - sD22[lane * 8 + k];
        s = fmaf(d, d, s);
      }
    }
    contrib = sFv[lane] + sVv[lane] * sqrtf(s + 1e-12f);
    vsum = sVv[lane];
  }
#pragma unroll
  for (int off = 8; off >= 1; off >>= 1) {
    contrib += __shfl_down(contrib, off, 64);
    vsum += __shfl_down(vsum, off, 64);
  }
  if (lane == 0) {
    atomicAdd(&accum[0], contrib);
    atomicAdd(&accum[1], vsum);
    __threadfence();
    float o2 = atomicAdd(&accum[2], 1.0f);
    if (o2 == 511.0f) {  // last of 512 anchor-tile merges
      float tt = atomicAdd(&accum[0], 0.0f);
      float vv2 = atomicAdd(&accum[1], 0.0f);
      out[0] = tt / (vv2 + 1e-8f);
    }
  }
}

extern "C" void kernel_launch(void* const* d_in, const int* in_sizes, int n_in,
                              void* d_out, int out_size, void* d_ws, size_t ws_size,
                              hipStream_t stream) {
  (void)in_sizes; (void)n_in; (void)out_size;
  const float* kp1   = (const float*)d_in[0];
  const float* wkp1  = (const float*)d_in[1];
  const float* desc  = (const float*)d_in[2];
  const float* desc2 = (const float*)d_in[3];
  const float* homo  = (const float*)d_in[4];
  float* ws = (float*)d_ws;
  unsigned short* frag = (unsigned short*)(ws + OFF_FRAG);
  unsigned short* wdb  = (unsigned short*)(ws + OFF_WDB);
  float4* jA = (float4*)(ws + OFF_JA);
  float2* jB = (float2*)(ws + OFF_JB);
  float* pos = ws + OFF_POS;
  float* vis = ws + OFF_VIS;
  float* acc = ws + OFF_ACC;
  int* cnt   = (int*)(ws + OFF_CNT);
  float* parts = ws + OFF_PARTS;
  unsigned short* d2t = (unsigned short*)(ws + OFF_D2T);

  if (ws_size >= (size_t)OFF_END * 4) {
    transpose_desc2<<<600, 256, 0, stream>>>(desc2, d2t);
    prep_t<<<2048, 256, 0, stream>>>(kp1, wkp1, desc, d2t, homo,
                                     frag, wdb, jA, jB, pos, vis, acc, cnt);
  } else {
    prep_g<<<2048, 256, 0, stream>>>(kp1, wkp1, desc, desc2, homo,
                                     frag, wdb, jA, jB, pos, vis, acc, cnt);
  }
  loss_main<<<1024, 256, 0, stream>>>(frag, jA, jB, pos, vis, wdb,
                                      parts, cnt, acc, (float*)d_out);
}

// Round 10
// 205.592 us; speedup vs baseline: 1.4620x; 1.4620x over previous
//
#include <hip/hip_runtime.h>
#include <hip/hip_fp16.h>
#include <math.h>

#define NPTS 4096
#define CDIM 128
#define FH 120
#define FW 160
#define PIX (FH * FW)   // 19200

typedef __attribute__((ext_vector_type(8))) short short8_t;
typedef __attribute__((ext_vector_type(4))) float float4_t;
typedef __attribute__((ext_vector_type(2))) unsigned short ushort2_t;

// workspace layout (float offsets)
#define OFF_FRAG  0                    // [b][tile 256][chunk 8][lane 64][8 bf16] = 4MB
#define OFF_WDB   1048576              // wd row layout (d22 recompute)
#define OFF_JA    1572864              // float4/pt: (ky,kx,wky,wkx)
#define OFF_JB    1605632              // float2/pt: (|d1|^2, |wd|^2)
#define OFF_POS   1622016
#define OFF_VIS   1630208
#define OFF_ACC   1638400              // [0]=loss [1]=vis [2]=final counter
#define OFF_CNT   1638416              // 512 ints: per-anchor-tile half counters
#define OFF_PARTS 1638928              // 2 halves * 22 lists * 8192 anchors
#define OFF_D2T   1999376              // fp16 transposed desc2
#define OFF_END   4456976

__device__ __forceinline__ unsigned short f2bf(float f) {
  unsigned int u = __float_as_uint(f);
  u = (u + 0x7fffu + ((u >> 16) & 1u)) >> 16;  // RNE, no NaN in this data
  return (unsigned short)u;
}

__device__ __forceinline__ float wavesum(float v) {
#pragma unroll
  for (int off = 1; off < 64; off <<= 1) v += __shfl_xor(v, off, 64);
  return v;
}

// ---- desc2 [b][c][pix] f32 -> [b][pix][c] f16 ----
__global__ __launch_bounds__(256) void transpose_desc2(
    const float* __restrict__ d2, unsigned short* __restrict__ out) {
  __shared__ unsigned short tile[64][130];
  const int bp = blockIdx.x;            // 0..599
  const int b = bp / 300;
  const int p0 = (bp - b * 300) * 64;
  const int tid = threadIdx.x;
  const int grp = tid >> 6, lp = tid & 63;
#pragma unroll 4
  for (int r = 0; r < 32; ++r) {
    int c = (r << 2) | grp;
    float v = d2[((size_t)b * CDIM + c) * PIX + p0 + lp];
    tile[lp][c] = __half_as_ushort(__float2half(v));
  }
  __syncthreads();
  unsigned int* ob = (unsigned int*)(out + ((size_t)b * PIX + p0) * CDIM);
#pragma unroll
  for (int i = 0; i < 16; ++i) {
    int u = (i << 8) | tid;
    int p = u >> 6, cc = (u & 63) << 1;
    unsigned int lo = tile[p][cc], hi = tile[p][cc + 1];
    ob[u] = lo | (hi << 16);
  }
}

// shared tail of both prep variants (frag-stream + scalar writes)
#define PREP_TAIL() do {                                                        \
  {                                                                             \
    const int T = (p & (NPTS - 1)) >> 4, cRow = p & 15;                         \
    const int kcL = lane >> 4, quadL = (lane >> 2) & 3, jjL = (lane & 3) * 2;   \
    const size_t off = (size_t)(quadL * 16 + cRow) * 8 + jjL;                   \
    const size_t tb = (((size_t)b * 256 + T) * 2) * 4;                          \
    ushort2_t st; st.x = f2bf(d0); st.y = f2bf(d1v);                            \
    ushort2_t sw; sw.x = f2bf(e0); sw.y = f2bf(e1);                             \
    *(ushort2_t*)(frag + (tb + kcL) * 512 + off) = st;                          \
    *(ushort2_t*)(frag + (tb + 4 + kcL) * 512 + off) = sw;                      \
    ushort2_t swr; swr.x = f2bf(e0); swr.y = f2bf(e1);                          \
    *(ushort2_t*)(wdb + (size_t)p * CDIM + c2) = swr;                           \
  }                                                                             \
  float dd0 = d0 - e0, dd1 = d1v - e1;                                          \
  float ssp = wavesum(dd0 * dd0 + dd1 * dd1);                                   \
  if (lane == 0) {                                                              \
    pos[p] = sqrtf(ssp + 1e-12f);                                               \
    float ky = kp1[p * 2 + 0], kx = kp1[p * 2 + 1];                             \
    jA[p] = make_float4(ky, kx, y, x);                                          \
    jB[p] = make_float2(n1, n2);                                                \
    const float* h = homo + b * 9;                                              \
    float t0 = h[0] * kx + h[1] * ky + h[2];                                    \
    float t1 = h[3] * kx + h[4] * ky + h[5];                                    \
    float t2 = h[6] * kx + h[7] * ky + h[8];                                    \
    float qx = t0 / (t2 + 1e-8f), qy = t1 / (t2 + 1e-8f);                       \
    vis[p] = (qx >= 0.0f && qx < 1280.0f && qy >= 0.0f && qy < 960.0f)          \
                 ? 1.0f : 0.0f;                                                 \
  }                                                                             \
} while (0)

#define PREP_INIT() do {                                                        \
  if (blockIdx.x < 2) cnt[blockIdx.x * 256 + tid] = 0;                          \
  if (blockIdx.x == 2 && tid < 8) acc[tid] = 0.0f;                              \
} while (0)

__global__ __launch_bounds__(256) void prep_t(
    const float* __restrict__ kp1, const float* __restrict__ wkp1,
    const float* __restrict__ desc, const unsigned short* __restrict__ d2t,
    const float* __restrict__ homo,
    unsigned short* __restrict__ frag, unsigned short* __restrict__ wdb,
    float4* __restrict__ jA, float2* __restrict__ jB,
    float* __restrict__ pos, float* __restrict__ vis,
    float* __restrict__ acc, int* __restrict__ cnt) {
  const int tid = threadIdx.x;
  PREP_INIT();
  const int p = blockIdx.x * 4 + (tid >> 6);
  const int lane = tid & 63;
  const int b = p >> 12;
  const int c2 = lane * 2;

  float2 v = *(const float2*)(desc + (size_t)p * CDIM + c2);
  float ss = wavesum(v.x * v.x + v.y * v.y);
  float inv = 1.0f / (sqrtf(ss) + 1e-8f);
  float d0 = v.x * inv, d1v = v.y * inv;
  float n1 = ss * inv * inv;

  float y = wkp1[p * 2 + 0], x = wkp1[p * 2 + 1];
  float gy = fminf(fmaxf(y * 0.125f - 0.5f, 0.0f), (float)(FH - 1));
  float gx = fminf(fmaxf(x * 0.125f - 0.5f, 0.0f), (float)(FW - 1));
  int y0 = (int)floorf(gy); y0 = min(max(y0, 0), FH - 2);
  int x0 = (int)floorf(gx); x0 = min(max(x0, 0), FW - 2);
  float wy = gy - (float)y0, wx = gx - (float)x0;
  float w00 = (1 - wy) * (1 - wx), w01 = (1 - wy) * wx;
  float w10 = wy * (1 - wx), w11 = wy * wx;
  const unsigned int* t00 = (const unsigned int*)
      (d2t + ((size_t)b * PIX + y0 * FW + x0) * CDIM) + lane;
  unsigned int u00 = t00[0], u01 = t00[64];
  unsigned int u10 = t00[FW * 64], u11 = t00[FW * 64 + 64];
  float2 f00 = __half22float2(*(const __half2*)&u00);
  float2 f01 = __half22float2(*(const __half2*)&u01);
  float2 f10 = __half22float2(*(const __half2*)&u10);
  float2 f11 = __half22float2(*(const __half2*)&u11);
  float wv0 = f00.x * w00 + f01.x * w01 + f10.x * w10 + f11.x * w11;
  float wv1 = f00.y * w00 + f01.y * w01 + f10.y * w10 + f11.y * w11;
  float ss2 = wavesum(wv0 * wv0 + wv1 * wv1);
  float inv2 = 1.0f / (sqrtf(ss2) + 1e-8f);
  float e0 = wv0 * inv2, e1 = wv1 * inv2;
  float n2 = ss2 * inv2 * inv2;

  PREP_TAIL();
}

__global__ __launch_bounds__(256) void prep_g(
    const float* __restrict__ kp1, const float* __restrict__ wkp1,
    const float* __restrict__ desc, const float* __restrict__ desc2,
    const float* __restrict__ homo,
    unsigned short* __restrict__ frag, unsigned short* __restrict__ wdb,
    float4* __restrict__ jA, float2* __restrict__ jB,
    float* __restrict__ pos, float* __restrict__ vis,
    float* __restrict__ acc, int* __restrict__ cnt) {
  const int tid = threadIdx.x;
  PREP_INIT();
  const int p = blockIdx.x * 4 + (tid >> 6);
  const int lane = tid & 63;
  const int b = p >> 12;
  const int c2 = lane * 2;

  float2 v = *(const float2*)(desc + (size_t)p * CDIM + c2);
  float ss = wavesum(v.x * v.x + v.y * v.y);
  float inv = 1.0f / (sqrtf(ss) + 1e-8f);
  float d0 = v.x * inv, d1v = v.y * inv;
  float n1 = ss * inv * inv;

  float y = wkp1[p * 2 + 0], x = wkp1[p * 2 + 1];
  float gy = fminf(fmaxf(y * 0.125f - 0.5f, 0.0f), (float)(FH - 1));
  float gx = fminf(fmaxf(x * 0.125f - 0.5f, 0.0f), (float)(FW - 1));
  int y0 = (int)floorf(gy); y0 = min(max(y0, 0), FH - 2);
  int x0 = (int)floorf(gx); x0 = min(max(x0, 0), FW - 2);
  float wy = gy - (float)y0, wx = gx - (float)x0;
  float w00 = (1 - wy) * (1 - wx), w01 = (1 - wy) * wx;
  float w10 = wy * (1 - wx), w11 = wy * wx;
  const float* q0 = desc2 + ((size_t)b * CDIM + c2) * PIX + y0 * FW + x0;
  const float* q1 = q0 + PIX;
  float wv0 = q0[0] * w00 + q0[1] * w01 + q0[FW] * w10 + q0[FW + 1] * w11;
  float wv1 = q1[0] * w00 + q1[1] * w01 + q1[FW] * w10 + q1[FW + 1] * w11;
  float ss2 = wavesum(wv0 * wv0 + wv1 * wv1);
  float inv2 = 1.0f / (sqrtf(ss2) + 1e-8f);
  float e0 = wv0 * inv2, e1 = wv1 * inv2;
  float n2 = ss2 * inv2 * inv2;

  PREP_TAIL();
}

// ---- med3 branchless inserts (sorted descending) ----
__device__ __forceinline__ void ins4m(float v, float* L) {
  float p0 = L[0]; L[0] = fmaxf(L[0], v);
  float p1 = L[1]; L[1] = __builtin_amdgcn_fmed3f(p0, L[1], v);
  float p2 = L[2]; L[2] = __builtin_amdgcn_fmed3f(p1, L[2], v);
  L[3] = __builtin_amdgcn_fmed3f(p2, L[3], v);
}
__device__ __forceinline__ void ins6m(float v, float* L) {
  float p0 = L[0]; L[0] = fmaxf(L[0], v);
  float p1 = L[1]; L[1] = __builtin_amdgcn_fmed3f(p0, L[1], v);
  float p2 = L[2]; L[2] = __builtin_amdgcn_fmed3f(p1, L[2], v);
  float p3 = L[3]; L[3] = __builtin_amdgcn_fmed3f(p2, L[3], v);
  float p4 = L[4]; L[4] = __builtin_amdgcn_fmed3f(p3, L[4], v);
  L[5] = __builtin_amdgcn_fmed3f(p4, L[5], v);
}
__device__ __forceinline__ void ins10m(float v, float* L) {
  float p0 = L[0]; L[0] = fmaxf(L[0], v);
  float pk = p0;
#pragma unroll
  for (int k = 1; k < 9; ++k) {
    float cur = L[k];
    L[k] = __builtin_amdgcn_fmed3f(pk, cur, v);
    pk = cur;
  }
  L[9] = __builtin_amdgcn_fmed3f(pk, L[9], v);
}

__device__ __forceinline__ float packkey(float s, int j) {
  return __uint_as_float((__float_as_uint(s) & 0xFFFFF000u) | (unsigned)j);
}

__device__ __forceinline__ float bflo(unsigned int u) { return __uint_as_float(u << 16); }
__device__ __forceinline__ float bfhi(unsigned int u) { return __uint_as_float(u & 0xFFFF0000u); }

#define TILE_COMPUTE(AD, AW, NA, NB, J0) do {                                   \
  float4_t aD = {0,0,0,0}, aDt = {0,0,0,0}, a11 = {0,0,0,0};                    \
  _Pragma("unroll")                                                             \
  for (int kc = 0; kc < 4; ++kc) {                                              \
    aD  = __builtin_amdgcn_mfma_f32_16x16x32_bf16(AW[kc], Bd[kc], aD,  0,0,0);  \
    aDt = __builtin_amdgcn_mfma_f32_16x16x32_bf16(AD[kc], Bw[kc], aDt, 0,0,0);  \
    a11 = __builtin_amdgcn_mfma_f32_16x16x32_bf16(AD[kc], Bd[kc], a11, 0,0,0);  \
  }                                                                             \
  const float nj1[4] = {NA.x, NA.z, NB.x, NB.z};                                \
  const float nj2[4] = {NA.y, NA.w, NB.y, NB.w};                                \
  _Pragma("unroll")                                                             \
  for (int reg = 0; reg < 4; ++reg) {                                           \
    const int jj = (J0) + (quad << 2) + reg;                                    \
    ins4m(packkey(fmaf(2.0f, aD[reg],  -nj2[reg]), jj), fD);                    \
    ins4m(packkey(fmaf(2.0f, aDt[reg], -nj1[reg]), jj), fDt);                   \
    ins6m(packkey(fmaf(2.0f, a11[reg], -nj1[reg]), jj), fS);                    \
  }                                                                             \
} while (0)

// 1024 blocks x 256 threads (4 waves). bid = (b, half, g). Wave w sweeps 512 j
// (32 tiles) with the R8 register ping-pong. After the block's ladder merge,
// the last-arriving half merges both halves, post-filters, recomputes d22,
// and accumulates (fused merge_filter — saves a dispatch, ~44us of gap).
// launch_bounds(256,3): proven no-spill config (R7/R8).
__global__ __launch_bounds__(256, 3) void loss_main(
    const unsigned short* __restrict__ frag,
    const float4* __restrict__ jAg, const float2* __restrict__ jBg,
    const float* __restrict__ posg, const float* __restrict__ visg,
    const unsigned short* __restrict__ wdb,
    float* __restrict__ parts, int* __restrict__ cnt,
    float* __restrict__ accum, float* __restrict__ out) {
  __shared__ float mb[4][16][24];

  const int tid = threadIdx.x;
  const int bid = blockIdx.x;
  const int b = bid & 1;
  const int half = (bid >> 1) & 1;
  const int g = bid >> 2;                 // 0..255
  const int i0 = g * 16;
  const int wave = tid >> 6, lane = tid & 63;
  const int quad = lane >> 4;
  const int base = b * NPTS;

  // B fragments: anchors = tile g of this batch
  short8_t Bd[4], Bw[4];
  {
    const unsigned short* fb = frag + (((size_t)b * 256 + g) * 8) * 512 + (size_t)lane * 8;
#pragma unroll
    for (int kc = 0; kc < 4; ++kc) {
      Bd[kc] = *(const short8_t*)(fb + kc * 512);
      Bw[kc] = *(const short8_t*)(fb + (4 + kc) * 512);
    }
  }

  float fD[4], fDt[4], fS[6];
#pragma unroll
  for (int k = 0; k < 4; ++k) { fD[k] = -1e30f; fDt[k] = -1e30f; }
#pragma unroll
  for (int k = 0; k < 6; ++k) fS[k] = -1e30f;

  const int jstart = (half << 11) | (wave << 9);
  const unsigned short* fa = frag + (((size_t)b * 256 + (jstart >> 4)) * 8) * 512 + (size_t)lane * 8;
  const float2* jbb = jBg + base;

  short8_t A0d[4], A0w[4], A1d[4], A1w[4];
#pragma unroll
  for (int kc = 0; kc < 4; ++kc) {
    A0d[kc] = *(const short8_t*)(fa + kc * 512);
    A0w[kc] = *(const short8_t*)(fa + (4 + kc) * 512);
  }
  float4 n0a = *(const float4*)(jbb + jstart + (quad << 2));
  float4 n0b = *(const float4*)(jbb + jstart + (quad << 2) + 2);
  float4 n1a, n1b;

  for (int t = 0; t < 32; t += 2) {
    const unsigned short* f1 = fa + 4096;            // tile t+1
#pragma unroll
    for (int kc = 0; kc < 4; ++kc) {
      A1d[kc] = *(const short8_t*)(f1 + kc * 512);
      A1w[kc] = *(const short8_t*)(f1 + (4 + kc) * 512);
    }
    {
      const int j1 = jstart + ((t + 1) << 4);
      n1a = *(const float4*)(jbb + j1 + (quad << 2));
      n1b = *(const float4*)(jbb + j1 + (quad << 2) + 2);
    }
    TILE_COMPUTE(A0d, A0w, n0a, n0b, jstart + (t << 4));
    const unsigned short* f2 = fa + ((t + 2 < 32) ? 8192 : 0);   // tile t+2
#pragma unroll
    for (int kc = 0; kc < 4; ++kc) {
      A0d[kc] = *(const short8_t*)(f2 + kc * 512);
      A0w[kc] = *(const short8_t*)(f2 + (4 + kc) * 512);
    }
    {
      const int j2 = jstart + (((t + 2) & 31) << 4);
      n0a = *(const float4*)(jbb + j2 + (quad << 2));
      n0b = *(const float4*)(jbb + j2 + (quad << 2) + 2);
    }
    TILE_COMPUTE(A1d, A1w, n1a, n1b, jstart + ((t + 1) << 4));
    fa += 8192;
  }

  // expand to merge sizes 6/6/10
  float eD[6], eDt[6], eS[10];
#pragma unroll
  for (int k = 0; k < 4; ++k) { eD[k] = fD[k]; eDt[k] = fDt[k]; }
  eD[4] = eD[5] = eDt[4] = eDt[5] = -1e30f;
#pragma unroll
  for (int k = 0; k < 6; ++k) eS[k] = fS[k];
  eS[6] = eS[7] = eS[8] = eS[9] = -1e30f;

  // quad butterfly (same anchor class), snapshot first
  {
    float tmp[10];
#pragma unroll
    for (int off = 16; off <= 32; off <<= 1) {
#pragma unroll
      for (int k = 0; k < 6; ++k) tmp[k] = eD[k];
#pragma unroll
      for (int k = 0; k < 6; ++k) ins6m(__shfl_xor(tmp[k], off, 64), eD);
#pragma unroll
      for (int k = 0; k < 6; ++k) tmp[k] = eDt[k];
#pragma unroll
      for (int k = 0; k < 6; ++k) ins6m(__shfl_xor(tmp[k], off, 64), eDt);
#pragma unroll
      for (int k = 0; k < 10; ++k) tmp[k] = eS[k];
#pragma unroll
      for (int k = 0; k < 10; ++k) ins10m(__shfl_xor(tmp[k], off, 64), eS);
    }
  }

  // ladder merge across 4 waves -> wave 0
#pragma unroll
  for (int h2 = 2; h2 >= 1; h2 >>= 1) {
    if (wave >= h2 && wave < 2 * h2 && lane < 16) {
      float* m = &mb[wave][lane][0];
#pragma unroll
      for (int k = 0; k < 6; ++k) { m[k] = eD[k]; m[6 + k] = eDt[k]; }
#pragma unroll
      for (int k = 0; k < 10; ++k) m[12 + k] = eS[k];
    }
    __syncthreads();
    if (wave < h2 && lane < 16) {
      const float* m = &mb[wave + h2][lane][0];
#pragma unroll
      for (int k = 0; k < 6; ++k) ins6m(m[k], eD);
#pragma unroll
      for (int k = 0; k < 6; ++k) ins6m(m[6 + k], eDt);
#pragma unroll
      for (int k = 0; k < 10; ++k) ins10m(m[12 + k], eS);
    }
  }

  if (wave != 0) return;

  // publish this half's lists
  if (lane < 16) {
    const int a = base + i0 + lane;
    float* P = parts + (size_t)(half * 22) * 8192 + a;
#pragma unroll
    for (int k = 0; k < 6; ++k) {
      P[(size_t)k * 8192] = eD[k];
      P[(size_t)(6 + k) * 8192] = eDt[k];
    }
#pragma unroll
    for (int k = 0; k < 10; ++k) P[(size_t)(12 + k) * 8192] = eS[k];
  }
  __threadfence();          // release
  int old = 0;
  if (lane == 0) old = atomicAdd(&cnt[b * 256 + g], 1);
  old = __shfl(old, 0, 64);
  if (old != 1) return;
  __threadfence();          // acquire

  // ---- last half: merge other half, post-filter, d22, accumulate ----
  char* scr = (char*)&mb[0][0][0];   // waves 1-3 no longer touch mb
  int*   sJ   = (int*)scr;             // 128
  float* sD11 = (float*)(scr + 512);   // 128
  float* sD22 = (float*)(scr + 1024);  // 128
  float* sN2  = (float*)(scr + 1536);  // 16
  float* sFv  = (float*)(scr + 1600);  // 16
  float* sVv  = (float*)(scr + 1664);  // 16

  if (lane < 16) {
    const int a = base + i0 + lane;
    const float* Q = parts + (size_t)((half ^ 1) * 22) * 8192 + a;
#pragma unroll
    for (int k = 0; k < 6; ++k) {
      ins6m(Q[(size_t)k * 8192], eD);
      ins6m(Q[(size_t)(6 + k) * 8192], eDt);
    }
#pragma unroll
    for (int k = 0; k < 10; ++k) ins10m(Q[(size_t)(12 + k) * 8192], eS);

    const float4 own = jAg[a];
    const float2 nb = jBg[a];
    const float pv = posg[a], vv = visg[a];
    float t1s = 0.0f, t2s = 0.0f;
    int got = 0;
#pragma unroll
    for (int k = 0; k < 6; ++k) {
      int j = (int)(__float_as_uint(eD[k]) & 0xFFFu);
      float4 jc = jAg[base + j];
      float dz = own.z - jc.z, dw = own.w - jc.w;
      if (got < 4 && dz * dz + dw * dw > 256.0f) {
        float d2 = nb.x - eD[k];
        t1s += fmaxf(1.0f + pv - sqrtf(fmaxf(d2, 1e-12f)), 0.0f);
        got++;
      }
    }
    got = 0;
#pragma unroll
    for (int k = 0; k < 6; ++k) {
      int j = (int)(__float_as_uint(eDt[k]) & 0xFFFu);
      float4 jc = jAg[base + j];
      float dz = own.z - jc.z, dw = own.w - jc.w;
      if (got < 4 && dz * dz + dw * dw > 256.0f) {
        float d2 = nb.y - eDt[k];
        t2s += fmaxf(1.0f + pv - sqrtf(fmaxf(d2, 1e-12f)), 0.0f);
        got++;
      }
    }
    int m = 0;
#pragma unroll
    for (int k = 0; k < 10; ++k) {
      int j = (int)(__float_as_uint(eS[k]) & 0xFFFu);
      float4 jc = jAg[base + j];
      float ay = own.x - jc.x, ax = own.y - jc.y;
      float wz = own.z - jc.z, ww = own.w - jc.w;
      if (m < 8 && ay * ay + ax * ax > 256.0f && wz * wz + ww * ww > 256.0f) {
        sJ[lane * 8 + m] = base + j;
        sD11[lane * 8 + m] = sqrtf(fmaxf(nb.x - eS[k], 1e-12f));
        m++;
      }
    }
    for (int k = m; k < 8; ++k) sJ[lane * 8 + k] = -1;
    sFv[lane] = vv * 0.125f * (t1s + t2s);
    sVv[lane] = vv;
    sN2[lane] = nb.y;
  }
  asm volatile("" ::: "memory");  // single-wave: DS pipe in-order; block compiler reorder

  // d22 for survivors: 128 slots, 2 per lane
#pragma unroll
  for (int rep = 0; rep < 2; ++rep) {
    const int slot = lane + rep * 64;
    const int al = slot >> 3;
    const int j = sJ[slot];
    float d22 = 0.0f;
    if (j >= 0) {
      const uint4* pi = (const uint4*)(wdb + (size_t)(base + i0 + al) * CDIM);
      const uint4* pj = (const uint4*)(wdb + (size_t)j * CDIM);
      float dot = 0.0f;
#pragma unroll
      for (int qq = 0; qq < 16; ++qq) {
        uint4 ui = pi[qq], uj = pj[qq];
        dot = fmaf(bflo(ui.x), bflo(uj.x), dot); dot = fmaf(bfhi(ui.x), bfhi(uj.x), dot);
        dot = fmaf(bflo(ui.y), bflo(uj.y), dot); dot = fmaf(bfhi(ui.y), bfhi(uj.y), dot);
        dot = fmaf(bflo(ui.z), bflo(uj.z), dot); dot = fmaf(bfhi(ui.z), bfhi(uj.z), dot);
        dot = fmaf(bflo(ui.w), bflo(uj.w), dot); dot = fmaf(bfhi(ui.w), bfhi(uj.w), dot);
      }
      d22 = sqrtf(fmaxf(sN2[al] + jBg[j].y - 2.0f * dot, 1e-12f));
    }
    sD22[slot] = d22;
  }
  asm volatile("" ::: "memory");

  float contrib = 0.0f, vsum = 0.0f;
  if (lane < 16) {
    float s = 0.0f;
#pragma unroll
    for (int k = 0; k < 8; ++k) {
      if (sJ[lane * 8 + k] >= 0) {
        float d = sD11[lane * 8 + k] - sD22[lane * 8 + k];
        s = fmaf(d, d, s);
      }
    }
    contrib = sFv[lane] + sVv[lane] * sqrtf(s + 1e-12f);
    vsum = sVv[lane];
  }
#pragma unroll
  for (int off = 8; off >= 1; off >>= 1) {
    contrib += __shfl_down(contrib, off, 64);
    vsum += __shfl_down(vsum, off, 64);
  }
  if (lane == 0) {
    atomicAdd(&accum[0], contrib);
    atomicAdd(&accum[1], vsum);
    __threadfence();
    float o2 = atomicAdd(&accum[2], 1.0f);
    if (o2 == 511.0f) {  // last of 512 anchor-tile merges
      float tt = atomicAdd(&accum[0], 0.0f);
      float vv2 = atomicAdd(&accum[1], 0.0f);
      out[0] = tt / (vv2 + 1e-8f);
    }
  }
}

extern "C" void kernel_launch(void* const* d_in, const int* in_sizes, int n_in,
                              void* d_out, int out_size, void* d_ws, size_t ws_size,
                              hipStream_t stream) {
  (void)in_sizes; (void)n_in; (void)out_size;
  const float* kp1   = (const float*)d_in[0];
  const float* wkp1  = (const float*)d_in[1];
  const float* desc  = (const float*)d_in[2];
  const float* desc2 = (const float*)d_in[3];
  const float* homo  = (const float*)d_in[4];
  float* ws = (float*)d_ws;
  unsigned short* frag = (unsigned short*)(ws + OFF_FRAG);
  unsigned short* wdb  = (unsigned short*)(ws + OFF_WDB);
  float4* jA = (float4*)(ws + OFF_JA);
  float2* jB = (float2*)(ws + OFF_JB);
  float* pos = ws + OFF_POS;
  float* vis = ws + OFF_VIS;
  float* acc = ws + OFF_ACC;
  int* cnt   = (int*)(ws + OFF_CNT);
  float* parts = ws + OFF_PARTS;
  unsigned short* d2t = (unsigned short*)(ws + OFF_D2T);

  if (ws_size >= (size_t)OFF_END * 4) {
    transpose_desc2<<<600, 256, 0, stream>>>(desc2, d2t);
    prep_t<<<2048, 256, 0, stream>>>(kp1, wkp1, desc, d2t, homo,
                                     frag, wdb, jA, jB, pos, vis, acc, cnt);
  } else {
    prep_g<<<2048, 256, 0, stream>>>(kp1, wkp1, desc, desc2, homo,
                                     frag, wdb, jA, jB, pos, vis, acc, cnt);
  }
  loss_main<<<1024, 256, 0, stream>>>(frag, jA, jB, pos, vis, wdb,
                                      parts, cnt, acc, (float*)d_out);
}